// Round 2
// baseline (1521.215 us; speedup 1.0000x reference)
//
#include <hip/hip_runtime.h>
#include <cstddef>

#define N_NODES 12288
#define SIG     2048
#define C1N     16
#define L1N     1024
#define C2N     32
#define L2N     512
#define F0      64
#define F1      128
#define NEDGE   196608
#define NGRAPH  1024

#define C1T_S   65          // row stride of c1t [r][pg]
#define C1T_IC  1300        // 20 * 65 per local ic

// ---------------------------------------------------------------- encoder
// one block (256 threads) per node.
// conv2 register-tiled: thread = (og = tid>>6 -> 8 out-channels, pg = tid&63 -> 8 positions)
__global__ __launch_bounds__(256, 4) void k_encoder(
    const float* __restrict__ x_raw,
    const float* __restrict__ conv1_w, const float* __restrict__ conv1_b,
    const float* __restrict__ conv2_w, const float* __restrict__ conv2_b,
    const float* __restrict__ lin_w,   const float* __restrict__ lin_b,
    float* __restrict__ h0)
{
    __shared__ float  xs[2064];          // x[i] at xs[8+i], zero pads both sides
    __shared__ float  c1t[4 * C1T_IC];   // conv1 chunk, transposed: [icl][r][pg], stride 65
    __shared__ float4 wts4[80 * 8];      // conv2 weights: [(ic*5+t)*32 + oc] as float4 over oc
    __shared__ float  w1s[C1N * 8];      // conv1: 7 weights + bias per channel
    __shared__ float  mean_s[C2N];

    float* wts = (float*)wts4;
    const int tid  = threadIdx.x;
    const int node = blockIdx.x;
    const int pg   = tid & 63;           // positions 8*pg .. 8*pg+7
    const int og   = tid >> 6;           // out channels 8*og .. 8*og+7

    // stage conv2 weights transposed: wts[(ic*5+t)*32 + oc] = conv2_w[oc*80 + ic*5 + t]
    for (int i = tid; i < C2N * C1N * 5; i += 256) {
        int oc = i / 80;
        int r  = i - oc * 80;
        wts[r * 32 + oc] = conv2_w[i];
    }
    for (int i = tid; i < C1N * 8; i += 256) {
        int ic = i >> 3, t = i & 7;
        w1s[i] = (t < 7) ? conv1_w[ic * 7 + t] : conv1_b[ic];
    }
    {
        const float* xrow = x_raw + (size_t)node * SIG;
        for (int i = tid; i < 2064; i += 256) {
            int xi = i - 8;
            xs[i] = (xi >= 0 && xi < SIG) ? xrow[xi] : 0.f;
        }
    }

    float acc[8][8];
    #pragma unroll
    for (int o = 0; o < 8; ++o) {
        float b = conv2_b[8 * og + o];
        #pragma unroll
        for (int j = 0; j < 8; ++j) acc[j][o] = b;
    }
    __syncthreads();

    #pragma unroll 1
    for (int phase = 0; phase < 4; ++phase) {
        // ---- conv1: fill c1t for global ic = 4*phase + icl, all 4 icl
        #pragma unroll
        for (int jj = 0; jj < 5; ++jj) {
            int idx = jj * 256 + tid;        // 0..1279
            int lpg = idx / 20;              // 0..63
            int lr  = idx - lpg * 20;        // 0..19
            int p   = (lpg << 4) + lr - 2;   // conv1 output position
            bool ok = (unsigned)p < (unsigned)L1N;
            const float* xp = &xs[2 * p + 5];
            float xv[7];
            #pragma unroll
            for (int t = 0; t < 7; ++t) xv[t] = xp[t];
            #pragma unroll
            for (int icl = 0; icl < 4; ++icl) {
                const float* w = &w1s[(4 * phase + icl) << 3];
                float a = w[7];
                #pragma unroll
                for (int t = 0; t < 7; ++t) a = fmaf(xv[t], w[t], a);
                c1t[icl * C1T_IC + lr * C1T_S + lpg] = ok ? fmaxf(a, 0.f) : 0.f;
            }
        }
        __syncthreads();

        // ---- conv2: consume the 4 channels
        #pragma unroll 1
        for (int icl = 0; icl < 4; ++icl) {
            const float* cb = &c1t[icl * C1T_IC + pg];
            float v[19];
            #pragma unroll
            for (int r = 0; r < 19; ++r) v[r] = cb[r * C1T_S];
            const int icg = 4 * phase + icl;
            #pragma unroll
            for (int t = 0; t < 5; ++t) {
                float4 wa = wts4[(icg * 5 + t) * 8 + 2 * og];      // broadcast
                float4 wb = wts4[(icg * 5 + t) * 8 + 2 * og + 1];  // broadcast
                #pragma unroll
                for (int j = 0; j < 8; ++j) {
                    float vv = v[2 * j + t];
                    acc[j][0] = fmaf(vv, wa.x, acc[j][0]);
                    acc[j][1] = fmaf(vv, wa.y, acc[j][1]);
                    acc[j][2] = fmaf(vv, wa.z, acc[j][2]);
                    acc[j][3] = fmaf(vv, wa.w, acc[j][3]);
                    acc[j][4] = fmaf(vv, wb.x, acc[j][4]);
                    acc[j][5] = fmaf(vv, wb.y, acc[j][5]);
                    acc[j][6] = fmaf(vv, wb.z, acc[j][6]);
                    acc[j][7] = fmaf(vv, wb.w, acc[j][7]);
                }
            }
        }
        __syncthreads();   // before next phase overwrites c1t
    }

    // ---- relu + mean: wave og covers all 512 positions for oc 8*og..8*og+7
    #pragma unroll
    for (int o = 0; o < 8; ++o) {
        float s = 0.f;
        #pragma unroll
        for (int j = 0; j < 8; ++j) s += fmaxf(acc[j][o], 0.f);
        s += __shfl_down(s, 32);
        s += __shfl_down(s, 16);
        s += __shfl_down(s, 8);
        s += __shfl_down(s, 4);
        s += __shfl_down(s, 2);
        s += __shfl_down(s, 1);
        if (pg == 0) mean_s[8 * og + o] = s * (1.f / 512.f);
    }
    __syncthreads();

    // ---- linear 32 -> 64
    if (tid < F0) {
        float a = lin_b[tid];
        #pragma unroll
        for (int ic = 0; ic < C2N; ++ic)
            a = fmaf(mean_s[ic], lin_w[ic * F0 + tid], a);
        h0[(size_t)node * F0 + tid] = a;
    }
}

// ---------------------------------------------------------------- degree
__global__ __launch_bounds__(256) void k_count(const int* __restrict__ dst,
                                               int* __restrict__ deg)
{
    int e = blockIdx.x * 256 + threadIdx.x;
    if (e < NEDGE) atomicAdd(&deg[dst[e]], 1);
}

__global__ __launch_bounds__(256) void k_dis(const int* __restrict__ deg,
                                             float* __restrict__ dis,
                                             float* __restrict__ invd)
{
    int n = blockIdx.x * 256 + threadIdx.x;
    if (n < N_NODES) {
        float d = (float)(deg[n] + 1);   // +1 self loop
        dis[n]  = rsqrtf(d);
        invd[n] = 1.f / d;
    }
}

// ---------------------------------------------------------------- h @ W (K -> 128)
__global__ __launch_bounds__(256) void k_gemm(const float* __restrict__ h,
                                              const float* __restrict__ W,
                                              float* __restrict__ out, int K)
{
    __shared__ float hs[2][F1];
    const int tid = threadIdx.x;
    const int n0  = blockIdx.x * 2;
    const int r   = tid >> 7;
    const int j   = tid & 127;

    if (tid < 2 * K) {
        int nn = (tid >= K) ? 1 : 0;
        int kk = tid - nn * K;
        hs[nn][kk] = h[(size_t)(n0 + nn) * K + kk];
    }
    __syncthreads();

    float a = 0.f;
    for (int k = 0; k < K; ++k)
        a = fmaf(hs[r][k], W[k * F1 + j], a);
    out[(size_t)(n0 + r) * F1 + j] = a;
}

// ---------------------------------------------------------------- edge aggregation (push, atomics)
__global__ __launch_bounds__(256) void k_edge(const int* __restrict__ src,
                                              const int* __restrict__ dst,
                                              const float* __restrict__ dis,
                                              const float* __restrict__ tmp,
                                              float* __restrict__ agg)
{
    int t = blockIdx.x * 256 + threadIdx.x;
    int e = t >> 7;
    int f = t & 127;
    if (e < NEDGE) {
        int s = src[e], d = dst[e];
        float nv = dis[s] * dis[d];
        atomicAdd(&agg[(size_t)d * F1 + f], tmp[(size_t)s * F1 + f] * nv);
    }
}

// ---------------------------------------------------------------- self term + bias + relu
__global__ __launch_bounds__(256) void k_finish(const float* __restrict__ agg,
                                                const float* __restrict__ tmp,
                                                const float* __restrict__ invd,
                                                const float* __restrict__ b,
                                                float* __restrict__ hout)
{
    int t = blockIdx.x * 256 + threadIdx.x;   // < N_NODES*F1
    int n = t >> 7, f = t & 127;
    float v = agg[t] + tmp[t] * invd[n] + b[f];
    hout[t] = fmaxf(v, 0.f);
}

// ---------------------------------------------------------------- mean pool per graph
__global__ __launch_bounds__(256) void k_pool(const float* __restrict__ h2,
                                              const int* __restrict__ batch,
                                              float* __restrict__ pooled,
                                              float* __restrict__ cnt)
{
    int t = blockIdx.x * 256 + threadIdx.x;   // < N_NODES*F1
    int n = t >> 7, f = t & 127;
    int g = batch[n];
    atomicAdd(&pooled[(size_t)g * F1 + f], h2[t]);
    if (f == 0) atomicAdd(&cnt[g], 1.f);
}

// ---------------------------------------------------------------- final FC 128 -> 5
__global__ __launch_bounds__(128) void k_final(const float* __restrict__ pooled,
                                               const float* __restrict__ cnt,
                                               const float* __restrict__ fc_w,
                                               const float* __restrict__ fc_b,
                                               float* __restrict__ out)
{
    __shared__ float ps[F1];
    const int g = blockIdx.x, tid = threadIdx.x;
    float inv = 1.f / fmaxf(cnt[g], 1.f);
    ps[tid] = pooled[g * F1 + tid] * inv;
    __syncthreads();
    if (tid < 5) {
        float a = fc_b[tid];
        for (int f = 0; f < F1; ++f) a = fmaf(ps[f], fc_w[f * 5 + tid], a);
        out[g * 5 + tid] = a;
    }
}

// ---------------------------------------------------------------- launch
extern "C" void kernel_launch(void* const* d_in, const int* in_sizes, int n_in,
                              void* d_out, int out_size, void* d_ws, size_t ws_size,
                              hipStream_t stream)
{
    const float* x_raw = (const float*)d_in[0];
    const float* c1w   = (const float*)d_in[1];
    const float* c1b   = (const float*)d_in[2];
    const float* c2w   = (const float*)d_in[3];
    const float* c2b   = (const float*)d_in[4];
    const float* lw    = (const float*)d_in[5];
    const float* lb    = (const float*)d_in[6];
    const float* g1w   = (const float*)d_in[7];
    const float* g1b   = (const float*)d_in[8];
    const float* g2w   = (const float*)d_in[9];
    const float* g2b   = (const float*)d_in[10];
    const float* fcw   = (const float*)d_in[11];
    const float* fcb   = (const float*)d_in[12];
    const int*   ei    = (const int*)d_in[13];
    const int*   batch = (const int*)d_in[14];
    const int* src = ei;
    const int* dst = ei + NEDGE;

    float* ws = (float*)d_ws;
    float* h0     = ws + 0;               // 786432
    float* tmp    = ws + 786432;          // 1572864
    float* agg    = ws + 2359296;         // 1572864
    float* h1     = ws + 3932160;         // 1572864
    float* h2     = ws + 5505024;         // 1572864
    float* dis    = ws + 7077888;         // 12288
    float* invd   = ws + 7090176;         // 12288
    float* pooled = ws + 7102464;         // 131072
    float* cnt    = ws + 7233536;         // 1024
    int*   deg    = (int*)(ws + 7234560); // 12288 ints

    float* out = (float*)d_out;

    hipMemsetAsync(deg, 0, N_NODES * sizeof(int), stream);
    k_encoder<<<N_NODES, 256, 0, stream>>>(x_raw, c1w, c1b, c2w, c2b, lw, lb, h0);
    k_count<<<(NEDGE + 255) / 256, 256, 0, stream>>>(dst, deg);
    k_dis<<<(N_NODES + 255) / 256, 256, 0, stream>>>(deg, dis, invd);

    // GCN layer 1
    k_gemm<<<N_NODES / 2, 256, 0, stream>>>(h0, g1w, tmp, F0);
    hipMemsetAsync(agg, 0, (size_t)N_NODES * F1 * sizeof(float), stream);
    k_edge<<<NEDGE / 2, 256, 0, stream>>>(src, dst, dis, tmp, agg);
    k_finish<<<N_NODES * F1 / 256, 256, 0, stream>>>(agg, tmp, invd, g1b, h1);

    // GCN layer 2
    k_gemm<<<N_NODES / 2, 256, 0, stream>>>(h1, g2w, tmp, F1);
    hipMemsetAsync(agg, 0, (size_t)N_NODES * F1 * sizeof(float), stream);
    k_edge<<<NEDGE / 2, 256, 0, stream>>>(src, dst, dis, tmp, agg);
    k_finish<<<N_NODES * F1 / 256, 256, 0, stream>>>(agg, tmp, invd, g2b, h2);

    // pool + fc
    hipMemsetAsync(pooled, 0, (size_t)(NGRAPH * F1 + NGRAPH) * sizeof(float), stream);
    k_pool<<<N_NODES * F1 / 256, 256, 0, stream>>>(h2, batch, pooled, cnt);
    k_final<<<NGRAPH, 128, 0, stream>>>(pooled, cnt, fcw, fcb, out);
}

// Round 3
// 804.464 us; speedup vs baseline: 1.8910x; 1.8910x over previous
//
#include <hip/hip_runtime.h>
#include <cstddef>

#define N_NODES 12288
#define SIG     2048
#define C1N     16
#define L1N     1024
#define C2N     32
#define L2N     512
#define F0      64
#define F1      128
#define NEDGE   196608
#define NGRAPH  1024

#define C1T_S   65          // row stride of c1t [r][pg]
#define C1T_IC  1300        // 20 * 65 per local ic

// ---------------------------------------------------------------- encoder
// one block (256 threads) per node.
// conv2 register-tiled: thread = (og = tid>>6 -> 8 out-channels, pg = tid&63 -> 8 positions)
// NOTE: no min-waves hint — with LDS=39.9KB the backend targets 4 blocks/CU -> 128-VGPR cap.
// Round-2 lesson: __launch_bounds__(256,4) drove a 64-VGPR target and spilled acc[8][8]
// to scratch (2.8 GB WRITE_SIZE/dispatch).
__global__ __launch_bounds__(256) void k_encoder(
    const float* __restrict__ x_raw,
    const float* __restrict__ conv1_w, const float* __restrict__ conv1_b,
    const float* __restrict__ conv2_w, const float* __restrict__ conv2_b,
    const float* __restrict__ lin_w,   const float* __restrict__ lin_b,
    float* __restrict__ h0)
{
    __shared__ float  xs[2064];          // x[i] at xs[8+i], zero pads both sides
    __shared__ float  c1t[4 * C1T_IC];   // conv1 chunk, transposed: [icl][r][pg], stride 65
    __shared__ float4 wts4[80 * 8];      // conv2 weights: [(ic*5+t)*32 + oc] as float4 over oc
    __shared__ float  w1s[C1N * 8];      // conv1: 7 weights + bias per channel
    __shared__ float  mean_s[C2N];

    float* wts = (float*)wts4;
    const int tid  = threadIdx.x;
    const int node = blockIdx.x;
    const int pg   = tid & 63;           // positions 8*pg .. 8*pg+7
    const int og   = tid >> 6;           // out channels 8*og .. 8*og+7

    // stage conv2 weights transposed: wts[(ic*5+t)*32 + oc] = conv2_w[oc*80 + ic*5 + t]
    for (int i = tid; i < C2N * C1N * 5; i += 256) {
        int oc = i / 80;
        int r  = i - oc * 80;
        wts[r * 32 + oc] = conv2_w[i];
    }
    for (int i = tid; i < C1N * 8; i += 256) {
        int ic = i >> 3, t = i & 7;
        w1s[i] = (t < 7) ? conv1_w[ic * 7 + t] : conv1_b[ic];
    }
    {
        const float* xrow = x_raw + (size_t)node * SIG;
        for (int i = tid; i < 2064; i += 256) {
            int xi = i - 8;
            xs[i] = (xi >= 0 && xi < SIG) ? xrow[xi] : 0.f;
        }
    }

    float acc[8][8];
    #pragma unroll
    for (int o = 0; o < 8; ++o) {
        float b = conv2_b[8 * og + o];
        #pragma unroll
        for (int j = 0; j < 8; ++j) acc[j][o] = b;
    }
    __syncthreads();

    #pragma unroll 1
    for (int phase = 0; phase < 4; ++phase) {
        // ---- conv1: fill c1t for global ic = 4*phase + icl, all 4 icl
        #pragma unroll
        for (int jj = 0; jj < 5; ++jj) {
            int idx = jj * 256 + tid;        // 0..1279
            int lpg = idx / 20;              // 0..63
            int lr  = idx - lpg * 20;        // 0..19
            int p   = (lpg << 4) + lr - 2;   // conv1 output position
            bool ok = (unsigned)p < (unsigned)L1N;
            const float* xp = &xs[2 * p + 5];
            float xv[7];
            #pragma unroll
            for (int t = 0; t < 7; ++t) xv[t] = xp[t];
            #pragma unroll
            for (int icl = 0; icl < 4; ++icl) {
                const float* w = &w1s[(4 * phase + icl) << 3];
                float a = w[7];
                #pragma unroll
                for (int t = 0; t < 7; ++t) a = fmaf(xv[t], w[t], a);
                c1t[icl * C1T_IC + lr * C1T_S + lpg] = ok ? fmaxf(a, 0.f) : 0.f;
            }
        }
        __syncthreads();

        // ---- conv2: consume the 4 channels
        #pragma unroll 1
        for (int icl = 0; icl < 4; ++icl) {
            const float* cb = &c1t[icl * C1T_IC + pg];
            float v[19];
            #pragma unroll
            for (int r = 0; r < 19; ++r) v[r] = cb[r * C1T_S];
            const int icg = 4 * phase + icl;
            #pragma unroll
            for (int t = 0; t < 5; ++t) {
                float4 wa = wts4[(icg * 5 + t) * 8 + 2 * og];      // broadcast
                float4 wb = wts4[(icg * 5 + t) * 8 + 2 * og + 1];  // broadcast
                #pragma unroll
                for (int j = 0; j < 8; ++j) {
                    float vv = v[2 * j + t];
                    acc[j][0] = fmaf(vv, wa.x, acc[j][0]);
                    acc[j][1] = fmaf(vv, wa.y, acc[j][1]);
                    acc[j][2] = fmaf(vv, wa.z, acc[j][2]);
                    acc[j][3] = fmaf(vv, wa.w, acc[j][3]);
                    acc[j][4] = fmaf(vv, wb.x, acc[j][4]);
                    acc[j][5] = fmaf(vv, wb.y, acc[j][5]);
                    acc[j][6] = fmaf(vv, wb.z, acc[j][6]);
                    acc[j][7] = fmaf(vv, wb.w, acc[j][7]);
                }
            }
        }
        __syncthreads();   // before next phase overwrites c1t
    }

    // ---- relu + mean: wave og covers all 512 positions for oc 8*og..8*og+7
    #pragma unroll
    for (int o = 0; o < 8; ++o) {
        float s = 0.f;
        #pragma unroll
        for (int j = 0; j < 8; ++j) s += fmaxf(acc[j][o], 0.f);
        s += __shfl_down(s, 32);
        s += __shfl_down(s, 16);
        s += __shfl_down(s, 8);
        s += __shfl_down(s, 4);
        s += __shfl_down(s, 2);
        s += __shfl_down(s, 1);
        if (pg == 0) mean_s[8 * og + o] = s * (1.f / 512.f);
    }
    __syncthreads();

    // ---- linear 32 -> 64
    if (tid < F0) {
        float a = lin_b[tid];
        #pragma unroll
        for (int ic = 0; ic < C2N; ++ic)
            a = fmaf(mean_s[ic], lin_w[ic * F0 + tid], a);
        h0[(size_t)node * F0 + tid] = a;
    }
}

// ---------------------------------------------------------------- degree
__global__ __launch_bounds__(256) void k_count(const int* __restrict__ dst,
                                               int* __restrict__ deg)
{
    int e = blockIdx.x * 256 + threadIdx.x;
    if (e < NEDGE) atomicAdd(&deg[dst[e]], 1);
}

__global__ __launch_bounds__(256) void k_dis(const int* __restrict__ deg,
                                             float* __restrict__ dis,
                                             float* __restrict__ invd)
{
    int n = blockIdx.x * 256 + threadIdx.x;
    if (n < N_NODES) {
        float d = (float)(deg[n] + 1);   // +1 self loop
        dis[n]  = rsqrtf(d);
        invd[n] = 1.f / d;
    }
}

// ---------------------------------------------------------------- h @ W (K -> 128)
__global__ __launch_bounds__(256) void k_gemm(const float* __restrict__ h,
                                              const float* __restrict__ W,
                                              float* __restrict__ out, int K)
{
    __shared__ float hs[2][F1];
    const int tid = threadIdx.x;
    const int n0  = blockIdx.x * 2;
    const int r   = tid >> 7;
    const int j   = tid & 127;

    if (tid < 2 * K) {
        int nn = (tid >= K) ? 1 : 0;
        int kk = tid - nn * K;
        hs[nn][kk] = h[(size_t)(n0 + nn) * K + kk];
    }
    __syncthreads();

    float a = 0.f;
    for (int k = 0; k < K; ++k)
        a = fmaf(hs[r][k], W[k * F1 + j], a);
    out[(size_t)(n0 + r) * F1 + j] = a;
}

// ---------------------------------------------------------------- edge aggregation (push, atomics)
__global__ __launch_bounds__(256) void k_edge(const int* __restrict__ src,
                                              const int* __restrict__ dst,
                                              const float* __restrict__ dis,
                                              const float* __restrict__ tmp,
                                              float* __restrict__ agg)
{
    int t = blockIdx.x * 256 + threadIdx.x;
    int e = t >> 7;
    int f = t & 127;
    if (e < NEDGE) {
        int s = src[e], d = dst[e];
        float nv = dis[s] * dis[d];
        atomicAdd(&agg[(size_t)d * F1 + f], tmp[(size_t)s * F1 + f] * nv);
    }
}

// ---------------------------------------------------------------- self term + bias + relu
__global__ __launch_bounds__(256) void k_finish(const float* __restrict__ agg,
                                                const float* __restrict__ tmp,
                                                const float* __restrict__ invd,
                                                const float* __restrict__ b,
                                                float* __restrict__ hout)
{
    int t = blockIdx.x * 256 + threadIdx.x;   // < N_NODES*F1
    int n = t >> 7, f = t & 127;
    float v = agg[t] + tmp[t] * invd[n] + b[f];
    hout[t] = fmaxf(v, 0.f);
}

// ---------------------------------------------------------------- mean pool per graph
__global__ __launch_bounds__(256) void k_pool(const float* __restrict__ h2,
                                              const int* __restrict__ batch,
                                              float* __restrict__ pooled,
                                              float* __restrict__ cnt)
{
    int t = blockIdx.x * 256 + threadIdx.x;   // < N_NODES*F1
    int n = t >> 7, f = t & 127;
    int g = batch[n];
    atomicAdd(&pooled[(size_t)g * F1 + f], h2[t]);
    if (f == 0) atomicAdd(&cnt[g], 1.f);
}

// ---------------------------------------------------------------- final FC 128 -> 5
__global__ __launch_bounds__(128) void k_final(const float* __restrict__ pooled,
                                               const float* __restrict__ cnt,
                                               const float* __restrict__ fc_w,
                                               const float* __restrict__ fc_b,
                                               float* __restrict__ out)
{
    __shared__ float ps[F1];
    const int g = blockIdx.x, tid = threadIdx.x;
    float inv = 1.f / fmaxf(cnt[g], 1.f);
    ps[tid] = pooled[g * F1 + tid] * inv;
    __syncthreads();
    if (tid < 5) {
        float a = fc_b[tid];
        for (int f = 0; f < F1; ++f) a = fmaf(ps[f], fc_w[f * 5 + tid], a);
        out[g * 5 + tid] = a;
    }
}

// ---------------------------------------------------------------- launch
extern "C" void kernel_launch(void* const* d_in, const int* in_sizes, int n_in,
                              void* d_out, int out_size, void* d_ws, size_t ws_size,
                              hipStream_t stream)
{
    const float* x_raw = (const float*)d_in[0];
    const float* c1w   = (const float*)d_in[1];
    const float* c1b   = (const float*)d_in[2];
    const float* c2w   = (const float*)d_in[3];
    const float* c2b   = (const float*)d_in[4];
    const float* lw    = (const float*)d_in[5];
    const float* lb    = (const float*)d_in[6];
    const float* g1w   = (const float*)d_in[7];
    const float* g1b   = (const float*)d_in[8];
    const float* g2w   = (const float*)d_in[9];
    const float* g2b   = (const float*)d_in[10];
    const float* fcw   = (const float*)d_in[11];
    const float* fcb   = (const float*)d_in[12];
    const int*   ei    = (const int*)d_in[13];
    const int*   batch = (const int*)d_in[14];
    const int* src = ei;
    const int* dst = ei + NEDGE;

    float* ws = (float*)d_ws;
    float* h0     = ws + 0;               // 786432
    float* tmp    = ws + 786432;          // 1572864
    float* agg    = ws + 2359296;         // 1572864
    float* h1     = ws + 3932160;         // 1572864
    float* h2     = ws + 5505024;         // 1572864
    float* dis    = ws + 7077888;         // 12288
    float* invd   = ws + 7090176;         // 12288
    float* pooled = ws + 7102464;         // 131072
    float* cnt    = ws + 7233536;         // 1024
    int*   deg    = (int*)(ws + 7234560); // 12288 ints

    float* out = (float*)d_out;

    hipMemsetAsync(deg, 0, N_NODES * sizeof(int), stream);
    k_encoder<<<N_NODES, 256, 0, stream>>>(x_raw, c1w, c1b, c2w, c2b, lw, lb, h0);
    k_count<<<(NEDGE + 255) / 256, 256, 0, stream>>>(dst, deg);
    k_dis<<<(N_NODES + 255) / 256, 256, 0, stream>>>(deg, dis, invd);

    // GCN layer 1
    k_gemm<<<N_NODES / 2, 256, 0, stream>>>(h0, g1w, tmp, F0);
    hipMemsetAsync(agg, 0, (size_t)N_NODES * F1 * sizeof(float), stream);
    k_edge<<<NEDGE / 2, 256, 0, stream>>>(src, dst, dis, tmp, agg);
    k_finish<<<N_NODES * F1 / 256, 256, 0, stream>>>(agg, tmp, invd, g1b, h1);

    // GCN layer 2
    k_gemm<<<N_NODES / 2, 256, 0, stream>>>(h1, g2w, tmp, F1);
    hipMemsetAsync(agg, 0, (size_t)N_NODES * F1 * sizeof(float), stream);
    k_edge<<<NEDGE / 2, 256, 0, stream>>>(src, dst, dis, tmp, agg);
    k_finish<<<N_NODES * F1 / 256, 256, 0, stream>>>(agg, tmp, invd, g2b, h2);

    // pool + fc
    hipMemsetAsync(pooled, 0, (size_t)(NGRAPH * F1 + NGRAPH) * sizeof(float), stream);
    k_pool<<<N_NODES * F1 / 256, 256, 0, stream>>>(h2, batch, pooled, cnt);
    k_final<<<NGRAPH, 128, 0, stream>>>(pooled, cnt, fcw, fcb, out);
}

// Round 4
// 634.436 us; speedup vs baseline: 2.3977x; 1.2680x over previous
//
#include <hip/hip_runtime.h>
#include <cstddef>

#define N_NODES 12288
#define SIG     2048
#define C1N     16
#define L1N     1024
#define C2N     32
#define L2N     512
#define F0      64
#define F1      128
#define NEDGE   196608
#define NGRAPH  1024

typedef float f32x4 __attribute__((ext_vector_type(4)));
typedef short s16x8 __attribute__((ext_vector_type(8)));

__device__ __forceinline__ unsigned short bf16_rtn(float f) {
    union { float f; unsigned u; } c; c.f = f;
    unsigned r = c.u + 0x7FFFu + ((c.u >> 16) & 1u);
    return (unsigned short)(r >> 16);
}
__device__ __forceinline__ float bf16_to_f(unsigned short h) {
    union { unsigned u; float f; } c; c.u = ((unsigned)h) << 16;
    return c.f;
}

// ---------------------------------------------------------------- encoder
// one block (256 threads = 4 waves) per node.
// conv1: fp32 VALU -> LDS as interleaved bf16 (hi,lo) pairs.
// conv2: split-bf16 MFMA GEMM  C[32 oc][512 pos] = W[32][80+pad16] x im2col(c1).
//   C ~= Whi*Bhi + Whi*Blo + Wlo*Bhi   (lo*lo dropped, rel err ~2^-17)
// mfma_f32_16x16x32_bf16 layouts (m89/m91): A: row=l&15,k=(l>>4)*8+j;
//   B: col=l&15,k=(l>>4)*8+j;  C/D: col=l&15,row=(l>>4)*4+reg.
__global__ __launch_bounds__(256) void k_encoder(
    const float* __restrict__ x_raw,
    const float* __restrict__ conv1_w, const float* __restrict__ conv1_b,
    const float* __restrict__ conv2_w, const float* __restrict__ conv2_b,
    const float* __restrict__ lin_w,   const float* __restrict__ lin_b,
    float* __restrict__ h0)
{
    __shared__ float xs[2064];            // x[i] at xs[8+i], zero-padded both sides
    __shared__ unsigned c1u[20 * 264];    // rows 0..15: c1 (hi|lo<<16); rows 16..19: zero K-pad
    __shared__ float w1s[C1N * 8];        // conv1: 7 weights + bias
    __shared__ float wmsum[4][C2N];
    __shared__ float mean_s[C2N];

    const unsigned short* c1s = (const unsigned short*)c1u;
    const int tid  = threadIdx.x;
    const int node = blockIdx.x;
    const int lane = tid & 63;
    const int wv   = tid >> 6;
    const int colL = lane & 15;           // col within 16-tile
    const int hi8  = lane >> 4;           // k-group / row-group

    // ---- stage xs, w1s, zero K-pad rows
    {
        const float* xrow = x_raw + (size_t)node * SIG;
        for (int i = tid; i < 2064; i += 256) {
            int xi = i - 8;
            xs[i] = (xi >= 0 && xi < SIG) ? xrow[xi] : 0.f;
        }
    }
    for (int i = tid; i < C1N * 8; i += 256) {
        int ic = i >> 3, t = i & 7;
        w1s[i] = (t < 7) ? conv1_w[ic * 7 + t] : conv1_b[ic];
    }
    for (int i = tid; i < 4 * 264; i += 256) c1u[16 * 264 + i] = 0u;

    // ---- A fragments: W hi/lo, 2 m-tiles x 3 k-tiles (K padded 80->96)
    s16x8 whi[2][3], wlo[2][3];
    #pragma unroll
    for (int mt = 0; mt < 2; ++mt) {
        const int oc = mt * 16 + colL;
        #pragma unroll
        for (int kt = 0; kt < 3; ++kt) {
            #pragma unroll
            for (int j = 0; j < 8; ++j) {
                int k = kt * 32 + hi8 * 8 + j;
                float w = (k < 80) ? conv2_w[oc * 80 + k] : 0.f;
                unsigned short h = bf16_rtn(w);
                whi[mt][kt][j] = (short)h;
                wlo[mt][kt][j] = (short)bf16_rtn(w - bf16_to_f(h));
            }
        }
    }
    // bias per accumulator slot: row = hi8*4 + r
    float bias[2][4];
    #pragma unroll
    for (int mt = 0; mt < 2; ++mt)
        #pragma unroll
        for (int r = 0; r < 4; ++r)
            bias[mt][r] = conv2_b[mt * 16 + hi8 * 4 + r];

    float msumr[2][4];
    #pragma unroll
    for (int mt = 0; mt < 2; ++mt)
        #pragma unroll
        for (int r = 0; r < 4; ++r) msumr[mt][r] = 0.f;

    __syncthreads();

    // ---- 4 phases of 128 output positions each
    #pragma unroll 1
    for (int phase = 0; phase < 4; ++phase) {
        const int P0 = 256 * phase;

        // conv1 -> c1 rows 0..15, slots s=0..263 (c1 pos = P0-2+s), bf16 hi|lo packed
        for (int i = tid; i < 16 * 264; i += 256) {
            int ic = i / 264;
            int s  = i - ic * 264;
            int P  = P0 - 2 + s;
            float v = 0.f;
            if ((unsigned)P < (unsigned)L1N) {
                const float* w  = &w1s[ic << 3];
                const float* xp = &xs[2 * P + 5];
                float a = w[7];
                #pragma unroll
                for (int t = 0; t < 7; ++t) a = fmaf(xp[t], w[t], a);
                v = fmaxf(a, 0.f);
            }
            unsigned short h = bf16_rtn(v);
            unsigned short l = bf16_rtn(v - bf16_to_f(h));
            c1u[ic * 264 + s] = (unsigned)h | ((unsigned)l << 16);
        }
        __syncthreads();

        // conv2 MFMA: wave wv covers n-tiles {2wv, 2wv+1} (cols 32wv..32wv+31)
        f32x4 acc[2][2];   // [nt][mt]
        #pragma unroll
        for (int nt = 0; nt < 2; ++nt)
            #pragma unroll
            for (int mt = 0; mt < 2; ++mt) {
                acc[nt][mt][0] = bias[mt][0]; acc[nt][mt][1] = bias[mt][1];
                acc[nt][mt][2] = bias[mt][2]; acc[nt][mt][3] = bias[mt][3];
            }

        #pragma unroll
        for (int kt = 0; kt < 3; ++kt) {
            #pragma unroll
            for (int nt = 0; nt < 2; ++nt) {
                s16x8 bh, bl;
                #pragma unroll
                for (int j = 0; j < 8; ++j) {
                    int k  = kt * 32 + hi8 * 8 + j;
                    int ic = k / 5;
                    int t  = k - 5 * ic;
                    // slot s = 64*wv + 32*nt + 2*colL + t  -> u16 elem idx
                    int bidx = (ic * 264 + 64 * wv + 2 * colL + t) * 2 + 128 * nt;
                    bh[j] = (short)c1s[bidx];
                    bl[j] = (short)c1s[bidx + 1];
                }
                #pragma unroll
                for (int mt = 0; mt < 2; ++mt) {
                    acc[nt][mt] = __builtin_amdgcn_mfma_f32_16x16x32_bf16(whi[mt][kt], bh, acc[nt][mt], 0, 0, 0);
                    acc[nt][mt] = __builtin_amdgcn_mfma_f32_16x16x32_bf16(whi[mt][kt], bl, acc[nt][mt], 0, 0, 0);
                    acc[nt][mt] = __builtin_amdgcn_mfma_f32_16x16x32_bf16(wlo[mt][kt], bh, acc[nt][mt], 0, 0, 0);
                }
            }
        }

        // relu + accumulate position-sum
        #pragma unroll
        for (int nt = 0; nt < 2; ++nt)
            #pragma unroll
            for (int mt = 0; mt < 2; ++mt)
                #pragma unroll
                for (int r = 0; r < 4; ++r)
                    msumr[mt][r] += fmaxf(acc[nt][mt][r], 0.f);

        __syncthreads();   // before next phase overwrites c1u
    }

    // ---- reduce over the 16 columns within each 16-lane group
    #pragma unroll
    for (int mt = 0; mt < 2; ++mt)
        #pragma unroll
        for (int r = 0; r < 4; ++r) {
            float s = msumr[mt][r];
            s += __shfl_xor(s, 1);
            s += __shfl_xor(s, 2);
            s += __shfl_xor(s, 4);
            s += __shfl_xor(s, 8);
            msumr[mt][r] = s;
        }
    if (colL == 0) {
        #pragma unroll
        for (int mt = 0; mt < 2; ++mt)
            #pragma unroll
            for (int r = 0; r < 4; ++r)
                wmsum[wv][mt * 16 + hi8 * 4 + r] = msumr[mt][r];
    }
    __syncthreads();

    if (tid < C2N) {
        float s = wmsum[0][tid] + wmsum[1][tid] + wmsum[2][tid] + wmsum[3][tid];
        mean_s[tid] = s * (1.f / 512.f);
    }
    __syncthreads();

    // ---- linear 32 -> 64
    if (tid < F0) {
        float a = lin_b[tid];
        #pragma unroll
        for (int ic = 0; ic < C2N; ++ic)
            a = fmaf(mean_s[ic], lin_w[ic * F0 + tid], a);
        h0[(size_t)node * F0 + tid] = a;
    }
}

// ---------------------------------------------------------------- degree
__global__ __launch_bounds__(256) void k_count(const int* __restrict__ dst,
                                               int* __restrict__ deg)
{
    int e = blockIdx.x * 256 + threadIdx.x;
    if (e < NEDGE) atomicAdd(&deg[dst[e]], 1);
}

__global__ __launch_bounds__(256) void k_dis(const int* __restrict__ deg,
                                             float* __restrict__ dis,
                                             float* __restrict__ invd)
{
    int n = blockIdx.x * 256 + threadIdx.x;
    if (n < N_NODES) {
        float d = (float)(deg[n] + 1);   // +1 self loop
        dis[n]  = rsqrtf(d);
        invd[n] = 1.f / d;
    }
}

// ---------------------------------------------------------------- h @ W (K -> 128)
__global__ __launch_bounds__(256) void k_gemm(const float* __restrict__ h,
                                              const float* __restrict__ W,
                                              float* __restrict__ out, int K)
{
    __shared__ float hs[2][F1];
    const int tid = threadIdx.x;
    const int n0  = blockIdx.x * 2;
    const int r   = tid >> 7;
    const int j   = tid & 127;

    if (tid < 2 * K) {
        int nn = (tid >= K) ? 1 : 0;
        int kk = tid - nn * K;
        hs[nn][kk] = h[(size_t)(n0 + nn) * K + kk];
    }
    __syncthreads();

    float a = 0.f;
    for (int k = 0; k < K; ++k)
        a = fmaf(hs[r][k], W[k * F1 + j], a);
    out[(size_t)(n0 + r) * F1 + j] = a;
}

// ---------------------------------------------------------------- edge aggregation (push, atomics)
__global__ __launch_bounds__(256) void k_edge(const int* __restrict__ src,
                                              const int* __restrict__ dst,
                                              const float* __restrict__ dis,
                                              const float* __restrict__ tmp,
                                              float* __restrict__ agg)
{
    int t = blockIdx.x * 256 + threadIdx.x;
    int e = t >> 7;
    int f = t & 127;
    if (e < NEDGE) {
        int s = src[e], d = dst[e];
        float nv = dis[s] * dis[d];
        atomicAdd(&agg[(size_t)d * F1 + f], tmp[(size_t)s * F1 + f] * nv);
    }
}

// ---------------------------------------------------------------- self term + bias + relu
__global__ __launch_bounds__(256) void k_finish(const float* __restrict__ agg,
                                                const float* __restrict__ tmp,
                                                const float* __restrict__ invd,
                                                const float* __restrict__ b,
                                                float* __restrict__ hout)
{
    int t = blockIdx.x * 256 + threadIdx.x;   // < N_NODES*F1
    int n = t >> 7, f = t & 127;
    float v = agg[t] + tmp[t] * invd[n] + b[f];
    hout[t] = fmaxf(v, 0.f);
}

// ---------------------------------------------------------------- mean pool per graph
__global__ __launch_bounds__(256) void k_pool(const float* __restrict__ h2,
                                              const int* __restrict__ batch,
                                              float* __restrict__ pooled,
                                              float* __restrict__ cnt)
{
    int t = blockIdx.x * 256 + threadIdx.x;   // < N_NODES*F1
    int n = t >> 7, f = t & 127;
    int g = batch[n];
    atomicAdd(&pooled[(size_t)g * F1 + f], h2[t]);
    if (f == 0) atomicAdd(&cnt[g], 1.f);
}

// ---------------------------------------------------------------- final FC 128 -> 5
__global__ __launch_bounds__(128) void k_final(const float* __restrict__ pooled,
                                               const float* __restrict__ cnt,
                                               const float* __restrict__ fc_w,
                                               const float* __restrict__ fc_b,
                                               float* __restrict__ out)
{
    __shared__ float ps[F1];
    const int g = blockIdx.x, tid = threadIdx.x;
    float inv = 1.f / fmaxf(cnt[g], 1.f);
    ps[tid] = pooled[g * F1 + tid] * inv;
    __syncthreads();
    if (tid < 5) {
        float a = fc_b[tid];
        for (int f = 0; f < F1; ++f) a = fmaf(ps[f], fc_w[f * 5 + tid], a);
        out[g * 5 + tid] = a;
    }
}

// ---------------------------------------------------------------- launch
extern "C" void kernel_launch(void* const* d_in, const int* in_sizes, int n_in,
                              void* d_out, int out_size, void* d_ws, size_t ws_size,
                              hipStream_t stream)
{
    const float* x_raw = (const float*)d_in[0];
    const float* c1w   = (const float*)d_in[1];
    const float* c1b   = (const float*)d_in[2];
    const float* c2w   = (const float*)d_in[3];
    const float* c2b   = (const float*)d_in[4];
    const float* lw    = (const float*)d_in[5];
    const float* lb    = (const float*)d_in[6];
    const float* g1w   = (const float*)d_in[7];
    const float* g1b   = (const float*)d_in[8];
    const float* g2w   = (const float*)d_in[9];
    const float* g2b   = (const float*)d_in[10];
    const float* fcw   = (const float*)d_in[11];
    const float* fcb   = (const float*)d_in[12];
    const int*   ei    = (const int*)d_in[13];
    const int*   batch = (const int*)d_in[14];
    const int* src = ei;
    const int* dst = ei + NEDGE;

    float* ws = (float*)d_ws;
    float* h0     = ws + 0;               // 786432
    float* tmp    = ws + 786432;          // 1572864
    float* agg    = ws + 2359296;         // 1572864
    float* h1     = ws + 3932160;         // 1572864
    float* h2     = ws + 5505024;         // 1572864
    float* dis    = ws + 7077888;         // 12288
    float* invd   = ws + 7090176;         // 12288
    float* pooled = ws + 7102464;         // 131072
    float* cnt    = ws + 7233536;         // 1024
    int*   deg    = (int*)(ws + 7234560); // 12288 ints

    float* out = (float*)d_out;

    hipMemsetAsync(deg, 0, N_NODES * sizeof(int), stream);
    k_encoder<<<N_NODES, 256, 0, stream>>>(x_raw, c1w, c1b, c2w, c2b, lw, lb, h0);
    k_count<<<(NEDGE + 255) / 256, 256, 0, stream>>>(dst, deg);
    k_dis<<<(N_NODES + 255) / 256, 256, 0, stream>>>(deg, dis, invd);

    // GCN layer 1
    k_gemm<<<N_NODES / 2, 256, 0, stream>>>(h0, g1w, tmp, F0);
    hipMemsetAsync(agg, 0, (size_t)N_NODES * F1 * sizeof(float), stream);
    k_edge<<<NEDGE / 2, 256, 0, stream>>>(src, dst, dis, tmp, agg);
    k_finish<<<N_NODES * F1 / 256, 256, 0, stream>>>(agg, tmp, invd, g1b, h1);

    // GCN layer 2
    k_gemm<<<N_NODES / 2, 256, 0, stream>>>(h1, g2w, tmp, F1);
    hipMemsetAsync(agg, 0, (size_t)N_NODES * F1 * sizeof(float), stream);
    k_edge<<<NEDGE / 2, 256, 0, stream>>>(src, dst, dis, tmp, agg);
    k_finish<<<N_NODES * F1 / 256, 256, 0, stream>>>(agg, tmp, invd, g2b, h2);

    // pool + fc
    hipMemsetAsync(pooled, 0, (size_t)(NGRAPH * F1 + NGRAPH) * sizeof(float), stream);
    k_pool<<<N_NODES * F1 / 256, 256, 0, stream>>>(h2, batch, pooled, cnt);
    k_final<<<NGRAPH, 128, 0, stream>>>(pooled, cnt, fcw, fcb, out);
}